// Round 3
// baseline (643.739 us; speedup 1.0000x reference)
//
#include <hip/hip_runtime.h>
#include <math.h>

#define Nn 50000
#define Ee 800000
#define Cc 96

// ============ prep: sort linear0 hidden units by relu threshold ============
// e(ea) = relu(ea*w0 + b0) @ W_l1 + b_l1 is piecewise-linear in scalar ea.
// Unit c active iff ea > t_c (w0>0) or ea < t_c (w0<0), t_c = -b0/w0.
// With thresholds sorted, k = #{t_i < ea} in [0,96] determines the active set.
__global__ void prep_sort_kernel(const float* __restrict__ Wl0, const float* __restrict__ bl0,
                                 float* __restrict__ st, float* __restrict__ sw,
                                 float* __restrict__ sb, int* __restrict__ so) {
    __shared__ float t_s[Cc];
    int c = threadIdx.x;
    float w = 0.f, b = 0.f, t = 0.f;
    if (c < Cc) {
        w = Wl0[c]; b = bl0[c];
        t = (w != 0.0f) ? (-b / w) : INFINITY;
        t_s[c] = t;
    }
    __syncthreads();
    if (c < Cc) {
        int r = 0;
        for (int j = 0; j < Cc; ++j) {
            float tj = t_s[j];
            r += (tj < t || (tj == t && j < c)) ? 1 : 0;  // stable rank sort
        }
        st[r] = t; sw[r] = w; sb[r] = b; so[r] = c;
    }
}

// Table: e[c2] = ea * A[k][c2] + B[k][c2], 97 patterns x 96 channels (75 KB).
__global__ void build_table_kernel(const float* __restrict__ sw, const float* __restrict__ sb,
                                   const int* __restrict__ so, const float* __restrict__ Wl1,
                                   const float* __restrict__ bl1,
                                   float* __restrict__ A, float* __restrict__ B) {
    int k = blockIdx.x;          // 0..96
    int c2 = threadIdx.x;
    if (c2 >= Cc) return;
    float a = 0.f, bacc = bl1[c2];
    for (int i = 0; i < Cc; ++i) {
        float w = sw[i], b = sb[i];
        float wv = Wl1[so[i] * Cc + c2];
        bool act = (w > 0.f) ? (i < k) : ((w < 0.f) ? (i >= k) : (b > 0.f));
        if (act) { a = fmaf(w, wv, a); bacc = fmaf(b, wv, bacc); }
    }
    A[k * Cc + c2] = a;
    B[k * Cc + c2] = bacc;
}

// ============ CSR build (by dst), reused for both convs ============
// NOTE: harness delivers integer inputs as int32 — edge_index is const int*.
__global__ void hist_kernel(const int* __restrict__ ei, int* __restrict__ counts) {
    int e = blockIdx.x * blockDim.x + threadIdx.x;
    if (e >= Ee) return;
    int d = ei[Ee + e];
    if ((unsigned)d >= (unsigned)Nn) return;   // defensive: drop bad edges
    atomicAdd(&counts[d], 1);
}

// single-block exclusive scan over 50000 counts -> rowptr, cursor
__global__ void scan_kernel(const int* __restrict__ counts, int* __restrict__ rowptr,
                            int* __restrict__ cursor) {
    __shared__ int lds[1024];
    int t = threadIdx.x;
    const int SEG = (Nn + 1023) / 1024;
    int base = t * SEG;
    int s = 0;
    for (int i = 0; i < SEG; ++i) {
        int idx = base + i;
        if (idx < Nn) s += counts[idx];
    }
    lds[t] = s;
    __syncthreads();
    for (int o = 1; o < 1024; o <<= 1) {
        int v = (t >= o) ? lds[t - o] : 0;
        __syncthreads();
        lds[t] += v;
        __syncthreads();
    }
    int run = lds[t] - s;   // exclusive prefix
    for (int i = 0; i < SEG; ++i) {
        int idx = base + i;
        if (idx < Nn) {
            rowptr[idx] = run; cursor[idx] = run;
            run += counts[idx];
        }
    }
    if (t == 1023) rowptr[Nn] = lds[1023];
}

// fill CSR: per edge store packed (src | k<<20) and ea; k found once here.
__global__ void fill_kernel(const int* __restrict__ ei, const float* __restrict__ eattr,
                            const float* __restrict__ st, int* __restrict__ cursor,
                            int* __restrict__ packed, float* __restrict__ eav) {
    __shared__ float ts[Cc];
    if (threadIdx.x < Cc) ts[threadIdx.x] = st[threadIdx.x];
    __syncthreads();
    int e = blockIdx.x * blockDim.x + threadIdx.x;
    if (e >= Ee) return;
    int s = ei[e];
    int d = ei[Ee + e];
    if ((unsigned)s >= (unsigned)Nn || (unsigned)d >= (unsigned)Nn) return;  // defensive
    float ea = eattr[e];
    int lo = 0, hi = Cc;          // k = count of thresholds < ea
    while (lo < hi) {
        int m = (lo + hi) >> 1;
        if (ts[m] < ea) lo = m + 1; else hi = m;
    }
    int pos = atomicAdd(&cursor[d], 1);
    if ((unsigned)pos >= (unsigned)Ee) return;  // defensive
    packed[pos] = s | (lo << 20);
    eav[pos] = ea;
}

// ============ aggregation: out[n] = feat[n] + sum_in relu(feat[src] + e) ============
// one 64-lane wave per node; lane covers channel lane, lanes<32 also 64+lane.
__global__ __launch_bounds__(256) void aggregate_kernel(
        const float* __restrict__ feat, const int* __restrict__ rowptr,
        const int* __restrict__ packed, const float* __restrict__ eav,
        const float* __restrict__ A, const float* __restrict__ B,
        float* __restrict__ out) {
    int node = blockIdx.x * (blockDim.x >> 6) + (threadIdx.x >> 6);
    int lane = threadIdx.x & 63;
    if (node >= Nn) return;
    bool lo32 = lane < 32;
    int cA = lane, cB = 64 + (lane & 31);
    size_t rowb = (size_t)node * Cc;
    float a0 = feat[rowb + cA];
    float a1 = lo32 ? feat[rowb + cB] : 0.f;
    int s = rowptr[node], e = rowptr[node + 1];
    for (int p = s; p < e; ++p) {
        int pk = packed[p];
        float ea = eav[p];
        int src = pk & 0xFFFFF;
        int kk = pk >> 20;
        const float* Ak = A + kk * Cc;
        const float* Bk = B + kk * Cc;
        size_t sbb = (size_t)src * Cc;
        float e0 = fmaf(ea, Ak[cA], Bk[cA]);
        float m0 = feat[sbb + cA] + e0;
        a0 += fmaxf(m0, 0.f);
        if (lo32) {
            float e1 = fmaf(ea, Ak[cB], Bk[cB]);
            float m1 = feat[sbb + cB] + e1;
            a1 += fmaxf(m1, 0.f);
        }
    }
    out[rowb + cA] = a0;
    if (lo32) out[rowb + cB] = a1;
}

// ============ fused 2-layer node MLP: out = relu(relu(in@W1+b1)@W2+b2) ============
// IN-PLACE SAFE: each block loads its 64 rows, syncs, computes, stores same rows.
// One weight LDS buffer, restaged W1 -> W2 between layers; layer-1 relu output
// overlaid onto the input tile. LDS ~61 KB -> 2 blocks/CU.
#define MLP_R 64
#define MLP_T 384
__global__ __launch_bounds__(MLP_T, 2) void mlp2_kernel(
        const float* __restrict__ in, const float* __restrict__ W1g, const float* __restrict__ b1g,
        const float* __restrict__ W2g, const float* __restrict__ b2g, float* __restrict__ out) {
    __shared__ __attribute__((aligned(16))) float inl[MLP_R * Cc];   // input tile, then relu1 tile
    __shared__ __attribute__((aligned(16))) float wt[Cc * Cc];       // W^T swizzled (W1 then W2)
    __shared__ float bb1[Cc], bb2[Cc];
    int tid = threadIdx.x;
    int row0 = blockIdx.x * MLP_R;

    // stage W1 transposed + XOR-swizzled: element (c2,c) at c2*96 + (c ^ 4*(c2&7))
    for (int idx = tid; idx < Cc * Cc; idx += MLP_T) {
        int c = idx / Cc, c2 = idx % Cc;       // coalesced read of W[c][c2]
        wt[c2 * Cc + (c ^ (4 * (c2 & 7)))] = W1g[idx];
    }
    if (tid < Cc) { bb1[tid] = b1g[tid]; bb2[tid] = b2g[tid]; }
    for (int idx = tid; idx < MLP_R * Cc; idx += MLP_T) {
        int r = row0 + idx / Cc;
        inl[idx] = (r < Nn) ? in[(size_t)r * Cc + idx % Cc] : 0.f;
    }
    __syncthreads();

    int ct = tid % 24;   // cols c2 = ct + 24*j, j=0..3
    int rt = tid / 24;   // rows r = rt*4 + i, i=0..3
    float acc[4][4];

    // ---- layer 1 ----
    for (int j = 0; j < 4; ++j) {
        float bv = bb1[ct + 24 * j];
        for (int i = 0; i < 4; ++i) acc[i][j] = bv;
    }
    for (int c = 0; c < Cc; c += 4) {
        float4 wv[4], xv[4];
        for (int j = 0; j < 4; ++j) {
            int c2 = ct + 24 * j;
            wv[j] = *(const float4*)&wt[c2 * Cc + (c ^ (4 * (c2 & 7)))];
        }
        for (int i = 0; i < 4; ++i)
            xv[i] = *(const float4*)&inl[(rt * 4 + i) * Cc + c];
        for (int i = 0; i < 4; ++i)
            for (int j = 0; j < 4; ++j) {
                acc[i][j] = fmaf(xv[i].x, wv[j].x, acc[i][j]);
                acc[i][j] = fmaf(xv[i].y, wv[j].y, acc[i][j]);
                acc[i][j] = fmaf(xv[i].z, wv[j].z, acc[i][j]);
                acc[i][j] = fmaf(xv[i].w, wv[j].w, acc[i][j]);
            }
    }
    __syncthreads();   // all reads of inl & wt done
    // overlay relu1 onto inl; restage wt with W2
    for (int j = 0; j < 4; ++j)
        for (int i = 0; i < 4; ++i)
            inl[(rt * 4 + i) * Cc + ct + 24 * j] = fmaxf(acc[i][j], 0.f);
    for (int idx = tid; idx < Cc * Cc; idx += MLP_T) {
        int c = idx / Cc, c2 = idx % Cc;
        wt[c2 * Cc + (c ^ (4 * (c2 & 7)))] = W2g[idx];
    }
    __syncthreads();

    // ---- layer 2 ----
    for (int j = 0; j < 4; ++j) {
        float bv = bb2[ct + 24 * j];
        for (int i = 0; i < 4; ++i) acc[i][j] = bv;
    }
    for (int c = 0; c < Cc; c += 4) {
        float4 wv[4], xv[4];
        for (int j = 0; j < 4; ++j) {
            int c2 = ct + 24 * j;
            wv[j] = *(const float4*)&wt[c2 * Cc + (c ^ (4 * (c2 & 7)))];
        }
        for (int i = 0; i < 4; ++i)
            xv[i] = *(const float4*)&inl[(rt * 4 + i) * Cc + c];
        for (int i = 0; i < 4; ++i)
            for (int j = 0; j < 4; ++j) {
                acc[i][j] = fmaf(xv[i].x, wv[j].x, acc[i][j]);
                acc[i][j] = fmaf(xv[i].y, wv[j].y, acc[i][j]);
                acc[i][j] = fmaf(xv[i].z, wv[j].z, acc[i][j]);
                acc[i][j] = fmaf(xv[i].w, wv[j].w, acc[i][j]);
            }
    }
    for (int i = 0; i < 4; ++i) {
        int r = row0 + rt * 4 + i;
        if (r < Nn)
            for (int j = 0; j < 4; ++j)
                out[(size_t)r * Cc + ct + 24 * j] = fmaxf(acc[i][j], 0.f);
    }
}

extern "C" void kernel_launch(void* const* d_in, const int* in_sizes, int n_in,
                              void* d_out, int out_size, void* d_ws, size_t ws_size,
                              hipStream_t stream) {
    const float* x     = (const float*)d_in[0];
    const int*   ei    = (const int*)d_in[1];     // int64 in ref -> int32 from harness
    const float* eattr = (const float*)d_in[2];
    const float* Wl0   = (const float*)d_in[3];
    const float* bl0   = (const float*)d_in[4];
    const float* Wl1   = (const float*)d_in[5];
    const float* bl1   = (const float*)d_in[6];
    const float* W00   = (const float*)d_in[7];
    const float* b00   = (const float*)d_in[8];
    const float* W01   = (const float*)d_in[9];
    const float* b01   = (const float*)d_in[10];
    const float* W10   = (const float*)d_in[11];
    const float* b10   = (const float*)d_in[12];
    const float* W11   = (const float*)d_in[13];
    const float* b11   = (const float*)d_in[14];
    float* outp = (float*)d_out;

    // workspace carve-up (~26 MB), 256B-aligned
    char* w = (char*)d_ws;
    size_t off = 0;
    auto alloc = [&](size_t bytes) { size_t r = off; off += (bytes + 255) & ~(size_t)255; return r; };
    int*   counts  = (int*)  (w + alloc((size_t)Nn * 4));
    int*   rowptr  = (int*)  (w + alloc((size_t)(Nn + 1) * 4));
    int*   cursor  = (int*)  (w + alloc((size_t)Nn * 4));
    int*   packed  = (int*)  (w + alloc((size_t)Ee * 4));
    float* eav     = (float*)(w + alloc((size_t)Ee * 4));
    float* st      = (float*)(w + alloc((size_t)Cc * 4));
    float* sw      = (float*)(w + alloc((size_t)Cc * 4));
    float* sb      = (float*)(w + alloc((size_t)Cc * 4));
    int*   so      = (int*)  (w + alloc((size_t)Cc * 4));
    float* A       = (float*)(w + alloc((size_t)(Cc + 1) * Cc * 4));
    float* B       = (float*)(w + alloc((size_t)(Cc + 1) * Cc * 4));
    float* hpre    = (float*)(w + alloc((size_t)Nn * Cc * 4));
    (void)ws_size; (void)in_sizes; (void)n_in; (void)out_size;

    hipMemsetAsync(counts, 0, (size_t)Nn * 4, stream);
    prep_sort_kernel<<<1, 128, 0, stream>>>(Wl0, bl0, st, sw, sb, so);
    build_table_kernel<<<Cc + 1, 128, 0, stream>>>(sw, sb, so, Wl1, bl1, A, B);
    hist_kernel<<<(Ee + 255) / 256, 256, 0, stream>>>(ei, counts);
    scan_kernel<<<1, 1024, 0, stream>>>(counts, rowptr, cursor);
    fill_kernel<<<(Ee + 255) / 256, 256, 0, stream>>>(ei, eattr, st, cursor, packed, eav);

    // conv 1: agg(x) -> hpre, mlp in-place on hpre
    aggregate_kernel<<<(Nn + 3) / 4, 256, 0, stream>>>(x, rowptr, packed, eav, A, B, hpre);
    mlp2_kernel<<<(Nn + MLP_R - 1) / MLP_R, MLP_T, 0, stream>>>(hpre, W00, b00, W01, b01, hpre);
    // conv 2: agg(hpre) -> d_out, mlp in-place on d_out
    aggregate_kernel<<<(Nn + 3) / 4, 256, 0, stream>>>(hpre, rowptr, packed, eav, A, B, outp);
    mlp2_kernel<<<(Nn + MLP_R - 1) / MLP_R, MLP_T, 0, stream>>>(outp, W10, b10, W11, b11, outp);
}

// Round 4
// 516.203 us; speedup vs baseline: 1.2471x; 1.2471x over previous
//
#include <hip/hip_runtime.h>
#include <math.h>

#define Nn 50000
#define Ee 800000
#define Cc 96

// ============ prep: sort linear0 hidden units by relu threshold ============
// e(ea) = relu(ea*w0 + b0) @ W_l1 + b_l1 is piecewise-linear in scalar ea.
// Unit c active iff ea > t_c (w0>0) or ea < t_c (w0<0), t_c = -b0/w0.
// With thresholds sorted, k = #{t_i < ea} in [0,96] determines the active set.
__global__ void prep_sort_kernel(const float* __restrict__ Wl0, const float* __restrict__ bl0,
                                 float* __restrict__ st, float* __restrict__ sw,
                                 float* __restrict__ sb, int* __restrict__ so) {
    __shared__ float t_s[Cc];
    int c = threadIdx.x;
    float w = 0.f, b = 0.f, t = 0.f;
    if (c < Cc) {
        w = Wl0[c]; b = bl0[c];
        t = (w != 0.0f) ? (-b / w) : INFINITY;
        t_s[c] = t;
    }
    __syncthreads();
    if (c < Cc) {
        int r = 0;
        for (int j = 0; j < Cc; ++j) {
            float tj = t_s[j];
            r += (tj < t || (tj == t && j < c)) ? 1 : 0;  // stable rank sort
        }
        st[r] = t; sw[r] = w; sb[r] = b; so[r] = c;
    }
}

// Table in gather-friendly layout: tab[k][j] = float4{A[2j], B[2j], A[2j+1], B[2j+1]},
// j = 0..47 channel pairs, k = 0..96 activation patterns. 75 KB.
__global__ void build_table_kernel(const float* __restrict__ sw, const float* __restrict__ sb,
                                   const int* __restrict__ so, const float* __restrict__ Wl1,
                                   const float* __restrict__ bl1,
                                   float* __restrict__ tabf) {
    int k = blockIdx.x;          // 0..96
    int c2 = threadIdx.x;
    if (c2 >= Cc) return;
    float a = 0.f, bacc = bl1[c2];
    for (int i = 0; i < Cc; ++i) {
        float w = sw[i], b = sb[i];
        float wv = Wl1[so[i] * Cc + c2];
        bool act = (w > 0.f) ? (i < k) : ((w < 0.f) ? (i >= k) : (b > 0.f));
        if (act) { a = fmaf(w, wv, a); bacc = fmaf(b, wv, bacc); }
    }
    int base = k * (2 * Cc) + (c2 >> 1) * 4 + ((c2 & 1) << 1);
    tabf[base] = a;
    tabf[base + 1] = bacc;
}

// ============ CSR build (by dst), reused for both convs ============
// NOTE: harness delivers integer inputs as int32 — edge_index is const int*.
__global__ void hist_kernel(const int* __restrict__ ei, int* __restrict__ counts) {
    int e = blockIdx.x * blockDim.x + threadIdx.x;
    if (e >= Ee) return;
    int d = ei[Ee + e];
    if ((unsigned)d >= (unsigned)Nn) return;   // defensive: drop bad edges
    atomicAdd(&counts[d], 1);
}

// single-block exclusive scan over 50000 counts -> rowptr, cursor
__global__ void scan_kernel(const int* __restrict__ counts, int* __restrict__ rowptr,
                            int* __restrict__ cursor) {
    __shared__ int lds[1024];
    int t = threadIdx.x;
    const int SEG = (Nn + 1023) / 1024;
    int base = t * SEG;
    int s = 0;
    for (int i = 0; i < SEG; ++i) {
        int idx = base + i;
        if (idx < Nn) s += counts[idx];
    }
    lds[t] = s;
    __syncthreads();
    for (int o = 1; o < 1024; o <<= 1) {
        int v = (t >= o) ? lds[t - o] : 0;
        __syncthreads();
        lds[t] += v;
        __syncthreads();
    }
    int run = lds[t] - s;   // exclusive prefix
    for (int i = 0; i < SEG; ++i) {
        int idx = base + i;
        if (idx < Nn) {
            rowptr[idx] = run; cursor[idx] = run;
            run += counts[idx];
        }
    }
    if (t == 1023) rowptr[Nn] = lds[1023];
}

// fill CSR: per edge store int2{ src | k<<20, bits(ea) }; k found once here.
__global__ void fill_kernel(const int* __restrict__ ei, const float* __restrict__ eattr,
                            const float* __restrict__ st, int* __restrict__ cursor,
                            int2* __restrict__ me) {
    __shared__ float ts[Cc];
    if (threadIdx.x < Cc) ts[threadIdx.x] = st[threadIdx.x];
    __syncthreads();
    int e = blockIdx.x * blockDim.x + threadIdx.x;
    if (e >= Ee) return;
    int s = ei[e];
    int d = ei[Ee + e];
    if ((unsigned)s >= (unsigned)Nn || (unsigned)d >= (unsigned)Nn) return;  // defensive
    float ea = eattr[e];
    int lo = 0, hi = Cc;          // k = count of thresholds < ea
    while (lo < hi) {
        int m = (lo + hi) >> 1;
        if (ts[m] < ea) lo = m + 1; else hi = m;
    }
    int pos = atomicAdd(&cursor[d], 1);
    if ((unsigned)pos >= (unsigned)Ee) return;  // defensive
    me[pos] = make_int2(s | (lo << 20), __float_as_int(ea));
}

// ============ aggregation: out[n] = feat[n] + sum_in relu(feat[src] + e) ============
// one 64-lane wave per node; lanes 0..47 each own a channel PAIR (float2).
// Per edge per lane: one 16B table load + one 8B feat load; meta is one
// wave-uniform 8B load. Edge loop unrolled x4 so 4 gather chains overlap.
__global__ __launch_bounds__(256) void aggregate_kernel(
        const float* __restrict__ feat, const int* __restrict__ rowptr,
        const int2* __restrict__ me, const float4* __restrict__ tab,
        float* __restrict__ out) {
    int node = blockIdx.x * (blockDim.x >> 6) + (threadIdx.x >> 6);
    int lane = threadIdx.x & 63;
    if (node >= Nn || lane >= 48) return;
    const float2* f2 = (const float2*)feat;
    int j = lane;                          // channel pair index, 0..47
    float2 acc = f2[(size_t)node * 48 + j];
    int s = rowptr[node], e = rowptr[node + 1];
    int p = s;
    for (; p + 4 <= e; p += 4) {
        int2 m0 = me[p], m1 = me[p + 1], m2 = me[p + 2], m3 = me[p + 3];
        float2 f0 = f2[(size_t)(m0.x & 0xFFFFF) * 48 + j];
        float2 f1 = f2[(size_t)(m1.x & 0xFFFFF) * 48 + j];
        float2 fq2 = f2[(size_t)(m2.x & 0xFFFFF) * 48 + j];
        float2 f3 = f2[(size_t)(m3.x & 0xFFFFF) * 48 + j];
        float4 t0 = tab[(m0.x >> 20) * 48 + j];
        float4 t1 = tab[(m1.x >> 20) * 48 + j];
        float4 t2 = tab[(m2.x >> 20) * 48 + j];
        float4 t3 = tab[(m3.x >> 20) * 48 + j];
        float ea0 = __int_as_float(m0.y), ea1 = __int_as_float(m1.y);
        float ea2 = __int_as_float(m2.y), ea3 = __int_as_float(m3.y);
        acc.x += fmaxf(f0.x + fmaf(ea0, t0.x, t0.y), 0.f);
        acc.y += fmaxf(f0.y + fmaf(ea0, t0.z, t0.w), 0.f);
        acc.x += fmaxf(f1.x + fmaf(ea1, t1.x, t1.y), 0.f);
        acc.y += fmaxf(f1.y + fmaf(ea1, t1.z, t1.w), 0.f);
        acc.x += fmaxf(fq2.x + fmaf(ea2, t2.x, t2.y), 0.f);
        acc.y += fmaxf(fq2.y + fmaf(ea2, t2.z, t2.w), 0.f);
        acc.x += fmaxf(f3.x + fmaf(ea3, t3.x, t3.y), 0.f);
        acc.y += fmaxf(f3.y + fmaf(ea3, t3.z, t3.w), 0.f);
    }
    for (; p < e; ++p) {
        int2 m0 = me[p];
        float2 f0 = f2[(size_t)(m0.x & 0xFFFFF) * 48 + j];
        float4 t0 = tab[(m0.x >> 20) * 48 + j];
        float ea0 = __int_as_float(m0.y);
        acc.x += fmaxf(f0.x + fmaf(ea0, t0.x, t0.y), 0.f);
        acc.y += fmaxf(f0.y + fmaf(ea0, t0.z, t0.w), 0.f);
    }
    ((float2*)out)[(size_t)node * 48 + j] = acc;
}

// ============ fused 2-layer node MLP: out = relu(relu(in@W1+b1)@W2+b2) ============
// IN-PLACE SAFE: each block loads its 64 rows, syncs, computes, stores same rows.
// One weight LDS buffer, restaged W1 -> W2 between layers; layer-1 relu output
// overlaid onto the input tile. LDS ~61 KB -> 2 blocks/CU.
#define MLP_R 64
#define MLP_T 384
__global__ __launch_bounds__(MLP_T, 2) void mlp2_kernel(
        const float* __restrict__ in, const float* __restrict__ W1g, const float* __restrict__ b1g,
        const float* __restrict__ W2g, const float* __restrict__ b2g, float* __restrict__ out) {
    __shared__ __attribute__((aligned(16))) float inl[MLP_R * Cc];   // input tile, then relu1 tile
    __shared__ __attribute__((aligned(16))) float wt[Cc * Cc];       // W^T swizzled (W1 then W2)
    __shared__ float bb1[Cc], bb2[Cc];
    int tid = threadIdx.x;
    int row0 = blockIdx.x * MLP_R;

    // stage W1 transposed + XOR-swizzled: element (c2,c) at c2*96 + (c ^ 4*(c2&7))
    for (int idx = tid; idx < Cc * Cc; idx += MLP_T) {
        int c = idx / Cc, c2 = idx % Cc;       // coalesced read of W[c][c2]
        wt[c2 * Cc + (c ^ (4 * (c2 & 7)))] = W1g[idx];
    }
    if (tid < Cc) { bb1[tid] = b1g[tid]; bb2[tid] = b2g[tid]; }
    for (int idx = tid; idx < MLP_R * Cc; idx += MLP_T) {
        int r = row0 + idx / Cc;
        inl[idx] = (r < Nn) ? in[(size_t)r * Cc + idx % Cc] : 0.f;
    }
    __syncthreads();

    int ct = tid % 24;   // cols c2 = ct + 24*j, j=0..3
    int rt = tid / 24;   // rows r = rt*4 + i, i=0..3
    float acc[4][4];

    // ---- layer 1 ----
    for (int j = 0; j < 4; ++j) {
        float bv = bb1[ct + 24 * j];
        for (int i = 0; i < 4; ++i) acc[i][j] = bv;
    }
    for (int c = 0; c < Cc; c += 4) {
        float4 wv[4], xv[4];
        for (int j = 0; j < 4; ++j) {
            int c2 = ct + 24 * j;
            wv[j] = *(const float4*)&wt[c2 * Cc + (c ^ (4 * (c2 & 7)))];
        }
        for (int i = 0; i < 4; ++i)
            xv[i] = *(const float4*)&inl[(rt * 4 + i) * Cc + c];
        for (int i = 0; i < 4; ++i)
            for (int j = 0; j < 4; ++j) {
                acc[i][j] = fmaf(xv[i].x, wv[j].x, acc[i][j]);
                acc[i][j] = fmaf(xv[i].y, wv[j].y, acc[i][j]);
                acc[i][j] = fmaf(xv[i].z, wv[j].z, acc[i][j]);
                acc[i][j] = fmaf(xv[i].w, wv[j].w, acc[i][j]);
            }
    }
    __syncthreads();   // all reads of inl & wt done
    // overlay relu1 onto inl; restage wt with W2
    for (int j = 0; j < 4; ++j)
        for (int i = 0; i < 4; ++i)
            inl[(rt * 4 + i) * Cc + ct + 24 * j] = fmaxf(acc[i][j], 0.f);
    for (int idx = tid; idx < Cc * Cc; idx += MLP_T) {
        int c = idx / Cc, c2 = idx % Cc;
        wt[c2 * Cc + (c ^ (4 * (c2 & 7)))] = W2g[idx];
    }
    __syncthreads();

    // ---- layer 2 ----
    for (int j = 0; j < 4; ++j) {
        float bv = bb2[ct + 24 * j];
        for (int i = 0; i < 4; ++i) acc[i][j] = bv;
    }
    for (int c = 0; c < Cc; c += 4) {
        float4 wv[4], xv[4];
        for (int j = 0; j < 4; ++j) {
            int c2 = ct + 24 * j;
            wv[j] = *(const float4*)&wt[c2 * Cc + (c ^ (4 * (c2 & 7)))];
        }
        for (int i = 0; i < 4; ++i)
            xv[i] = *(const float4*)&inl[(rt * 4 + i) * Cc + c];
        for (int i = 0; i < 4; ++i)
            for (int j = 0; j < 4; ++j) {
                acc[i][j] = fmaf(xv[i].x, wv[j].x, acc[i][j]);
                acc[i][j] = fmaf(xv[i].y, wv[j].y, acc[i][j]);
                acc[i][j] = fmaf(xv[i].z, wv[j].z, acc[i][j]);
                acc[i][j] = fmaf(xv[i].w, wv[j].w, acc[i][j]);
            }
    }
    for (int i = 0; i < 4; ++i) {
        int r = row0 + rt * 4 + i;
        if (r < Nn)
            for (int j = 0; j < 4; ++j)
                out[(size_t)r * Cc + ct + 24 * j] = fmaxf(acc[i][j], 0.f);
    }
}

extern "C" void kernel_launch(void* const* d_in, const int* in_sizes, int n_in,
                              void* d_out, int out_size, void* d_ws, size_t ws_size,
                              hipStream_t stream) {
    const float* x     = (const float*)d_in[0];
    const int*   ei    = (const int*)d_in[1];     // int64 in ref -> int32 from harness
    const float* eattr = (const float*)d_in[2];
    const float* Wl0   = (const float*)d_in[3];
    const float* bl0   = (const float*)d_in[4];
    const float* Wl1   = (const float*)d_in[5];
    const float* bl1   = (const float*)d_in[6];
    const float* W00   = (const float*)d_in[7];
    const float* b00   = (const float*)d_in[8];
    const float* W01   = (const float*)d_in[9];
    const float* b01   = (const float*)d_in[10];
    const float* W10   = (const float*)d_in[11];
    const float* b10   = (const float*)d_in[12];
    const float* W11   = (const float*)d_in[13];
    const float* b11   = (const float*)d_in[14];
    float* outp = (float*)d_out;

    // workspace carve-up (~26 MB), 256B-aligned
    char* w = (char*)d_ws;
    size_t off = 0;
    auto alloc = [&](size_t bytes) { size_t r = off; off += (bytes + 255) & ~(size_t)255; return r; };
    int*   counts  = (int*)  (w + alloc((size_t)Nn * 4));
    int*   rowptr  = (int*)  (w + alloc((size_t)(Nn + 1) * 4));
    int*   cursor  = (int*)  (w + alloc((size_t)Nn * 4));
    int2*  me      = (int2*) (w + alloc((size_t)Ee * 8));
    float* st      = (float*)(w + alloc((size_t)Cc * 4));
    float* sw      = (float*)(w + alloc((size_t)Cc * 4));
    float* sb      = (float*)(w + alloc((size_t)Cc * 4));
    int*   so      = (int*)  (w + alloc((size_t)Cc * 4));
    float* tabf    = (float*)(w + alloc((size_t)(Cc + 1) * 2 * Cc * 4));
    float* hpre    = (float*)(w + alloc((size_t)Nn * Cc * 4));
    (void)ws_size; (void)in_sizes; (void)n_in; (void)out_size;

    hipMemsetAsync(counts, 0, (size_t)Nn * 4, stream);
    prep_sort_kernel<<<1, 128, 0, stream>>>(Wl0, bl0, st, sw, sb, so);
    build_table_kernel<<<Cc + 1, 128, 0, stream>>>(sw, sb, so, Wl1, bl1, tabf);
    hist_kernel<<<(Ee + 255) / 256, 256, 0, stream>>>(ei, counts);
    scan_kernel<<<1, 1024, 0, stream>>>(counts, rowptr, cursor);
    fill_kernel<<<(Ee + 255) / 256, 256, 0, stream>>>(ei, eattr, st, cursor, me);

    const float4* tab = (const float4*)tabf;
    // conv 1: agg(x) -> hpre, mlp in-place on hpre
    aggregate_kernel<<<(Nn + 3) / 4, 256, 0, stream>>>(x, rowptr, me, tab, hpre);
    mlp2_kernel<<<(Nn + MLP_R - 1) / MLP_R, MLP_T, 0, stream>>>(hpre, W00, b00, W01, b01, hpre);
    // conv 2: agg(hpre) -> d_out, mlp in-place on d_out
    aggregate_kernel<<<(Nn + 3) / 4, 256, 0, stream>>>(hpre, rowptr, me, tab, outp);
    mlp2_kernel<<<(Nn + MLP_R - 1) / MLP_R, MLP_T, 0, stream>>>(outp, W10, b10, W11, b11, outp);
}

// Round 5
// 396.631 us; speedup vs baseline: 1.6230x; 1.3015x over previous
//
#include <hip/hip_runtime.h>
#include <math.h>

#define Nn 50000
#define Ee 800000
#define Cc 96

#define SCAN_B 256
#define SCAN_NB ((Nn + SCAN_B - 1) / SCAN_B)   // 196

// ============ prep: sort linear0 hidden units by relu threshold ============
// e(ea) = relu(ea*w0 + b0) @ W_l1 + b_l1 is piecewise-linear in scalar ea.
// Unit c active iff ea > t_c (w0>0) or ea < t_c (w0<0), t_c = -b0/w0.
// With thresholds sorted, k = #{t_i < ea} in [0,96] determines the active set.
__global__ void prep_sort_kernel(const float* __restrict__ Wl0, const float* __restrict__ bl0,
                                 float* __restrict__ st, float* __restrict__ sw,
                                 float* __restrict__ sb, int* __restrict__ so) {
    __shared__ float t_s[Cc];
    int c = threadIdx.x;
    float w = 0.f, b = 0.f, t = 0.f;
    if (c < Cc) {
        w = Wl0[c]; b = bl0[c];
        t = (w != 0.0f) ? (-b / w) : INFINITY;
        t_s[c] = t;
    }
    __syncthreads();
    if (c < Cc) {
        int r = 0;
        for (int j = 0; j < Cc; ++j) {
            float tj = t_s[j];
            r += (tj < t || (tj == t && j < c)) ? 1 : 0;  // stable rank sort
        }
        st[r] = t; sw[r] = w; sb[r] = b; so[r] = c;
    }
}

// Table in gather-friendly layout: tab[k][j] = float4{A[2j], B[2j], A[2j+1], B[2j+1]},
// j = 0..47 channel pairs, k = 0..96 activation patterns. 75 KB.
__global__ void build_table_kernel(const float* __restrict__ sw, const float* __restrict__ sb,
                                   const int* __restrict__ so, const float* __restrict__ Wl1,
                                   const float* __restrict__ bl1,
                                   float* __restrict__ tabf) {
    int k = blockIdx.x;          // 0..96
    int c2 = threadIdx.x;
    if (c2 >= Cc) return;
    float a = 0.f, bacc = bl1[c2];
    for (int i = 0; i < Cc; ++i) {
        float w = sw[i], b = sb[i];
        float wv = Wl1[so[i] * Cc + c2];
        bool act = (w > 0.f) ? (i < k) : ((w < 0.f) ? (i >= k) : (b > 0.f));
        if (act) { a = fmaf(w, wv, a); bacc = fmaf(b, wv, bacc); }
    }
    int base = k * (2 * Cc) + (c2 >> 1) * 4 + ((c2 & 1) << 1);
    tabf[base] = a;
    tabf[base + 1] = bacc;
}

// ============ CSR build (by dst), reused for both convs ============
// NOTE: harness delivers integer inputs as int32 — edge_index is const int*.
__global__ void hist_kernel(const int* __restrict__ ei, int* __restrict__ counts) {
    int e = blockIdx.x * blockDim.x + threadIdx.x;
    if (e >= Ee) return;
    int d = ei[Ee + e];
    if ((unsigned)d >= (unsigned)Nn) return;   // defensive: drop bad edges
    atomicAdd(&counts[d], 1);
}

// ---- 3-phase multi-block exclusive scan over counts[Nn] ----
// phase 1: per-block sum of 256 counts -> bsum[b]
__global__ __launch_bounds__(SCAN_B) void scan_sum_kernel(const int* __restrict__ counts,
                                                          int* __restrict__ bsum) {
    int i = blockIdx.x * SCAN_B + threadIdx.x;
    int v = (i < Nn) ? counts[i] : 0;
    for (int o = 32; o > 0; o >>= 1) v += __shfl_down(v, o, 64);
    __shared__ int ws[SCAN_B / 64];
    if ((threadIdx.x & 63) == 0) ws[threadIdx.x >> 6] = v;
    __syncthreads();
    if (threadIdx.x == 0) {
        int s = 0;
        for (int k = 0; k < SCAN_B / 64; ++k) s += ws[k];
        bsum[blockIdx.x] = s;
    }
}

// phase 2: single small block scans bsum[SCAN_NB] -> boff (exclusive), total -> rowptr[Nn]
__global__ __launch_bounds__(256) void scan_bsum_kernel(const int* __restrict__ bsum,
                                                        int* __restrict__ boff,
                                                        int* __restrict__ rowptr) {
    __shared__ int lds[256];
    int t = threadIdx.x;
    int v = (t < SCAN_NB) ? bsum[t] : 0;
    lds[t] = v;
    __syncthreads();
    for (int o = 1; o < 256; o <<= 1) {
        int u = (t >= o) ? lds[t - o] : 0;
        __syncthreads();
        lds[t] += u;
        __syncthreads();
    }
    if (t < SCAN_NB) boff[t] = lds[t] - v;
    if (t == 255) rowptr[Nn] = lds[255];
}

// phase 3: per-block exclusive scan of its 256 counts + boff -> rowptr, cursor
__global__ __launch_bounds__(SCAN_B) void scan_blocks_kernel(const int* __restrict__ counts,
                                                             const int* __restrict__ boff,
                                                             int* __restrict__ rowptr,
                                                             int* __restrict__ cursor) {
    __shared__ int lds[SCAN_B];
    int i = blockIdx.x * SCAN_B + threadIdx.x;
    int t = threadIdx.x;
    int v = (i < Nn) ? counts[i] : 0;
    lds[t] = v;
    __syncthreads();
    for (int o = 1; o < SCAN_B; o <<= 1) {
        int u = (t >= o) ? lds[t - o] : 0;
        __syncthreads();
        lds[t] += u;
        __syncthreads();
    }
    if (i < Nn) {
        int excl = lds[t] - v + boff[blockIdx.x];
        rowptr[i] = excl;
        cursor[i] = excl;
    }
}

// fill CSR: per edge store int2{ src | k<<20, bits(ea) }; k found once here.
__global__ void fill_kernel(const int* __restrict__ ei, const float* __restrict__ eattr,
                            const float* __restrict__ st, int* __restrict__ cursor,
                            int2* __restrict__ me) {
    __shared__ float ts[Cc];
    if (threadIdx.x < Cc) ts[threadIdx.x] = st[threadIdx.x];
    __syncthreads();
    int e = blockIdx.x * blockDim.x + threadIdx.x;
    if (e >= Ee) return;
    int s = ei[e];
    int d = ei[Ee + e];
    if ((unsigned)s >= (unsigned)Nn || (unsigned)d >= (unsigned)Nn) return;  // defensive
    float ea = eattr[e];
    int lo = 0, hi = Cc;          // k = count of thresholds < ea
    while (lo < hi) {
        int m = (lo + hi) >> 1;
        if (ts[m] < ea) lo = m + 1; else hi = m;
    }
    int pos = atomicAdd(&cursor[d], 1);
    if ((unsigned)pos >= (unsigned)Ee) return;  // defensive
    me[pos] = make_int2(s | (lo << 20), __float_as_int(ea));
}

// ============ aggregation: out[n] = feat[n] + sum_in relu(feat[src] + e) ============
// one 64-lane wave per node; lanes 0..47 each own a channel PAIR (float2).
// Per edge per lane: one 16B table load + one 8B feat load; meta is one
// wave-uniform 8B load. Edge loop unrolled x4 so 4 gather chains overlap.
__global__ __launch_bounds__(256) void aggregate_kernel(
        const float* __restrict__ feat, const int* __restrict__ rowptr,
        const int2* __restrict__ me, const float4* __restrict__ tab,
        float* __restrict__ out) {
    int node = blockIdx.x * (blockDim.x >> 6) + (threadIdx.x >> 6);
    int lane = threadIdx.x & 63;
    if (node >= Nn || lane >= 48) return;
    const float2* f2 = (const float2*)feat;
    int j = lane;                          // channel pair index, 0..47
    float2 acc = f2[(size_t)node * 48 + j];
    int s = rowptr[node], e = rowptr[node + 1];
    int p = s;
    for (; p + 4 <= e; p += 4) {
        int2 m0 = me[p], m1 = me[p + 1], m2 = me[p + 2], m3 = me[p + 3];
        float2 f0 = f2[(size_t)(m0.x & 0xFFFFF) * 48 + j];
        float2 f1 = f2[(size_t)(m1.x & 0xFFFFF) * 48 + j];
        float2 fq2 = f2[(size_t)(m2.x & 0xFFFFF) * 48 + j];
        float2 f3 = f2[(size_t)(m3.x & 0xFFFFF) * 48 + j];
        float4 t0 = tab[(m0.x >> 20) * 48 + j];
        float4 t1 = tab[(m1.x >> 20) * 48 + j];
        float4 t2 = tab[(m2.x >> 20) * 48 + j];
        float4 t3 = tab[(m3.x >> 20) * 48 + j];
        float ea0 = __int_as_float(m0.y), ea1 = __int_as_float(m1.y);
        float ea2 = __int_as_float(m2.y), ea3 = __int_as_float(m3.y);
        acc.x += fmaxf(f0.x + fmaf(ea0, t0.x, t0.y), 0.f);
        acc.y += fmaxf(f0.y + fmaf(ea0, t0.z, t0.w), 0.f);
        acc.x += fmaxf(f1.x + fmaf(ea1, t1.x, t1.y), 0.f);
        acc.y += fmaxf(f1.y + fmaf(ea1, t1.z, t1.w), 0.f);
        acc.x += fmaxf(fq2.x + fmaf(ea2, t2.x, t2.y), 0.f);
        acc.y += fmaxf(fq2.y + fmaf(ea2, t2.z, t2.w), 0.f);
        acc.x += fmaxf(f3.x + fmaf(ea3, t3.x, t3.y), 0.f);
        acc.y += fmaxf(f3.y + fmaf(ea3, t3.z, t3.w), 0.f);
    }
    for (; p < e; ++p) {
        int2 m0 = me[p];
        float2 f0 = f2[(size_t)(m0.x & 0xFFFFF) * 48 + j];
        float4 t0 = tab[(m0.x >> 20) * 48 + j];
        float ea0 = __int_as_float(m0.y);
        acc.x += fmaxf(f0.x + fmaf(ea0, t0.x, t0.y), 0.f);
        acc.y += fmaxf(f0.y + fmaf(ea0, t0.z, t0.w), 0.f);
    }
    ((float2*)out)[(size_t)node * 48 + j] = acc;
}

// ============ fused 2-layer node MLP: out = relu(relu(in@W1+b1)@W2+b2) ============
// IN-PLACE SAFE: each block loads its 64 rows, syncs, computes, stores same rows.
// One weight LDS buffer, restaged W1 -> W2 between layers; layer-1 relu output
// overlaid onto the input tile. LDS ~61 KB -> 2 blocks/CU.
#define MLP_R 64
#define MLP_T 384
__global__ __launch_bounds__(MLP_T, 2) void mlp2_kernel(
        const float* __restrict__ in, const float* __restrict__ W1g, const float* __restrict__ b1g,
        const float* __restrict__ W2g, const float* __restrict__ b2g, float* __restrict__ out) {
    __shared__ __attribute__((aligned(16))) float inl[MLP_R * Cc];   // input tile, then relu1 tile
    __shared__ __attribute__((aligned(16))) float wt[Cc * Cc];       // W^T swizzled (W1 then W2)
    __shared__ float bb1[Cc], bb2[Cc];
    int tid = threadIdx.x;
    int row0 = blockIdx.x * MLP_R;

    // stage W1 transposed + XOR-swizzled: element (c2,c) at c2*96 + (c ^ 4*(c2&7))
    for (int idx = tid; idx < Cc * Cc; idx += MLP_T) {
        int c = idx / Cc, c2 = idx % Cc;       // coalesced read of W[c][c2]
        wt[c2 * Cc + (c ^ (4 * (c2 & 7)))] = W1g[idx];
    }
    if (tid < Cc) { bb1[tid] = b1g[tid]; bb2[tid] = b2g[tid]; }
    for (int idx = tid; idx < MLP_R * Cc; idx += MLP_T) {
        int r = row0 + idx / Cc;
        inl[idx] = (r < Nn) ? in[(size_t)r * Cc + idx % Cc] : 0.f;
    }
    __syncthreads();

    int ct = tid % 24;   // cols c2 = ct + 24*j, j=0..3
    int rt = tid / 24;   // rows r = rt*4 + i, i=0..3
    float acc[4][4];

    // ---- layer 1 ----
    for (int j = 0; j < 4; ++j) {
        float bv = bb1[ct + 24 * j];
        for (int i = 0; i < 4; ++i) acc[i][j] = bv;
    }
    for (int c = 0; c < Cc; c += 4) {
        float4 wv[4], xv[4];
        for (int j = 0; j < 4; ++j) {
            int c2 = ct + 24 * j;
            wv[j] = *(const float4*)&wt[c2 * Cc + (c ^ (4 * (c2 & 7)))];
        }
        for (int i = 0; i < 4; ++i)
            xv[i] = *(const float4*)&inl[(rt * 4 + i) * Cc + c];
        for (int i = 0; i < 4; ++i)
            for (int j = 0; j < 4; ++j) {
                acc[i][j] = fmaf(xv[i].x, wv[j].x, acc[i][j]);
                acc[i][j] = fmaf(xv[i].y, wv[j].y, acc[i][j]);
                acc[i][j] = fmaf(xv[i].z, wv[j].z, acc[i][j]);
                acc[i][j] = fmaf(xv[i].w, wv[j].w, acc[i][j]);
            }
    }
    __syncthreads();   // all reads of inl & wt done
    // overlay relu1 onto inl; restage wt with W2
    for (int j = 0; j < 4; ++j)
        for (int i = 0; i < 4; ++i)
            inl[(rt * 4 + i) * Cc + ct + 24 * j] = fmaxf(acc[i][j], 0.f);
    for (int idx = tid; idx < Cc * Cc; idx += MLP_T) {
        int c = idx / Cc, c2 = idx % Cc;
        wt[c2 * Cc + (c ^ (4 * (c2 & 7)))] = W2g[idx];
    }
    __syncthreads();

    // ---- layer 2 ----
    for (int j = 0; j < 4; ++j) {
        float bv = bb2[ct + 24 * j];
        for (int i = 0; i < 4; ++i) acc[i][j] = bv;
    }
    for (int c = 0; c < Cc; c += 4) {
        float4 wv[4], xv[4];
        for (int j = 0; j < 4; ++j) {
            int c2 = ct + 24 * j;
            wv[j] = *(const float4*)&wt[c2 * Cc + (c ^ (4 * (c2 & 7)))];
        }
        for (int i = 0; i < 4; ++i)
            xv[i] = *(const float4*)&inl[(rt * 4 + i) * Cc + c];
        for (int i = 0; i < 4; ++i)
            for (int j = 0; j < 4; ++j) {
                acc[i][j] = fmaf(xv[i].x, wv[j].x, acc[i][j]);
                acc[i][j] = fmaf(xv[i].y, wv[j].y, acc[i][j]);
                acc[i][j] = fmaf(xv[i].z, wv[j].z, acc[i][j]);
                acc[i][j] = fmaf(xv[i].w, wv[j].w, acc[i][j]);
            }
    }
    for (int i = 0; i < 4; ++i) {
        int r = row0 + rt * 4 + i;
        if (r < Nn)
            for (int j = 0; j < 4; ++j)
                out[(size_t)r * Cc + ct + 24 * j] = fmaxf(acc[i][j], 0.f);
    }
}

extern "C" void kernel_launch(void* const* d_in, const int* in_sizes, int n_in,
                              void* d_out, int out_size, void* d_ws, size_t ws_size,
                              hipStream_t stream) {
    const float* x     = (const float*)d_in[0];
    const int*   ei    = (const int*)d_in[1];     // int64 in ref -> int32 from harness
    const float* eattr = (const float*)d_in[2];
    const float* Wl0   = (const float*)d_in[3];
    const float* bl0   = (const float*)d_in[4];
    const float* Wl1   = (const float*)d_in[5];
    const float* bl1   = (const float*)d_in[6];
    const float* W00   = (const float*)d_in[7];
    const float* b00   = (const float*)d_in[8];
    const float* W01   = (const float*)d_in[9];
    const float* b01   = (const float*)d_in[10];
    const float* W10   = (const float*)d_in[11];
    const float* b10   = (const float*)d_in[12];
    const float* W11   = (const float*)d_in[13];
    const float* b11   = (const float*)d_in[14];
    float* outp = (float*)d_out;

    // workspace carve-up (~26 MB), 256B-aligned
    char* w = (char*)d_ws;
    size_t off = 0;
    auto alloc = [&](size_t bytes) { size_t r = off; off += (bytes + 255) & ~(size_t)255; return r; };
    int*   counts  = (int*)  (w + alloc((size_t)Nn * 4));
    int*   rowptr  = (int*)  (w + alloc((size_t)(Nn + 1) * 4));
    int*   cursor  = (int*)  (w + alloc((size_t)Nn * 4));
    int2*  me      = (int2*) (w + alloc((size_t)Ee * 8));
    float* st      = (float*)(w + alloc((size_t)Cc * 4));
    float* sw      = (float*)(w + alloc((size_t)Cc * 4));
    float* sb      = (float*)(w + alloc((size_t)Cc * 4));
    int*   so      = (int*)  (w + alloc((size_t)Cc * 4));
    int*   bsum    = (int*)  (w + alloc((size_t)SCAN_NB * 4));
    int*   boff    = (int*)  (w + alloc((size_t)SCAN_NB * 4));
    float* tabf    = (float*)(w + alloc((size_t)(Cc + 1) * 2 * Cc * 4));
    float* hpre    = (float*)(w + alloc((size_t)Nn * Cc * 4));
    (void)ws_size; (void)in_sizes; (void)n_in; (void)out_size;

    hipMemsetAsync(counts, 0, (size_t)Nn * 4, stream);
    prep_sort_kernel<<<1, 128, 0, stream>>>(Wl0, bl0, st, sw, sb, so);
    build_table_kernel<<<Cc + 1, 128, 0, stream>>>(sw, sb, so, Wl1, bl1, tabf);
    hist_kernel<<<(Ee + 255) / 256, 256, 0, stream>>>(ei, counts);
    scan_sum_kernel<<<SCAN_NB, SCAN_B, 0, stream>>>(counts, bsum);
    scan_bsum_kernel<<<1, 256, 0, stream>>>(bsum, boff, rowptr);
    scan_blocks_kernel<<<SCAN_NB, SCAN_B, 0, stream>>>(counts, boff, rowptr, cursor);
    fill_kernel<<<(Ee + 255) / 256, 256, 0, stream>>>(ei, eattr, st, cursor, me);

    const float4* tab = (const float4*)tabf;
    // conv 1: agg(x) -> hpre, mlp in-place on hpre
    aggregate_kernel<<<(Nn + 3) / 4, 256, 0, stream>>>(x, rowptr, me, tab, hpre);
    mlp2_kernel<<<(Nn + MLP_R - 1) / MLP_R, MLP_T, 0, stream>>>(hpre, W00, b00, W01, b01, hpre);
    // conv 2: agg(hpre) -> d_out, mlp in-place on d_out
    aggregate_kernel<<<(Nn + 3) / 4, 256, 0, stream>>>(hpre, rowptr, me, tab, outp);
    mlp2_kernel<<<(Nn + MLP_R - 1) / MLP_R, MLP_T, 0, stream>>>(outp, W10, b10, W11, b11, outp);
}

// Round 6
// 316.920 us; speedup vs baseline: 2.0312x; 1.2515x over previous
//
#include <hip/hip_runtime.h>
#include <math.h>

#define Nn 50000
#define Ee 800000
#define Cc 96

#define SCAN_B 256
#define SCAN_NB ((Nn + SCAN_B - 1) / SCAN_B)   // 196

typedef __attribute__((ext_vector_type(8))) __bf16 bf16x8;
typedef __attribute__((ext_vector_type(4))) float f32x4;

// split fp32 into hi/lo bf16 (truncation; lo captures next 8 mantissa bits)
__device__ inline void split_bf16(float v, unsigned short& hi, unsigned short& lo) {
    unsigned u = __float_as_uint(v);
    hi = (unsigned short)(u >> 16);
    float rem = v - __uint_as_float(((unsigned)hi) << 16);
    lo = (unsigned short)(__float_as_uint(rem) >> 16);
}

// ============ prep: sort linear0 hidden units by relu threshold ============
// e(ea) = relu(ea*w0 + b0) @ W_l1 + b_l1 is piecewise-linear in scalar ea.
// Unit c active iff ea > t_c (w0>0) or ea < t_c (w0<0), t_c = -b0/w0.
// With thresholds sorted, k = #{t_i < ea} in [0,96] determines the active set.
__global__ void prep_sort_kernel(const float* __restrict__ Wl0, const float* __restrict__ bl0,
                                 float* __restrict__ st, float* __restrict__ sw,
                                 float* __restrict__ sb, int* __restrict__ so) {
    __shared__ float t_s[Cc];
    int c = threadIdx.x;
    float w = 0.f, b = 0.f, t = 0.f;
    if (c < Cc) {
        w = Wl0[c]; b = bl0[c];
        t = (w != 0.0f) ? (-b / w) : INFINITY;
        t_s[c] = t;
    }
    __syncthreads();
    if (c < Cc) {
        int r = 0;
        for (int j = 0; j < Cc; ++j) {
            float tj = t_s[j];
            r += (tj < t || (tj == t && j < c)) ? 1 : 0;  // stable rank sort
        }
        st[r] = t; sw[r] = w; sb[r] = b; so[r] = c;
    }
}

// Table in gather-friendly layout: tab[k][j] = float4{A[2j], B[2j], A[2j+1], B[2j+1]},
// j = 0..47 channel pairs, k = 0..96 activation patterns. 75 KB.
__global__ void build_table_kernel(const float* __restrict__ sw, const float* __restrict__ sb,
                                   const int* __restrict__ so, const float* __restrict__ Wl1,
                                   const float* __restrict__ bl1,
                                   float* __restrict__ tabf) {
    int k = blockIdx.x;          // 0..96
    int c2 = threadIdx.x;
    if (c2 >= Cc) return;
    float a = 0.f, bacc = bl1[c2];
    for (int i = 0; i < Cc; ++i) {
        float w = sw[i], b = sb[i];
        float wv = Wl1[so[i] * Cc + c2];
        bool act = (w > 0.f) ? (i < k) : ((w < 0.f) ? (i >= k) : (b > 0.f));
        if (act) { a = fmaf(w, wv, a); bacc = fmaf(b, wv, bacc); }
    }
    int base = k * (2 * Cc) + (c2 >> 1) * 4 + ((c2 & 1) << 1);
    tabf[base] = a;
    tabf[base + 1] = bacc;
}

// ============ CSR build (by dst), reused for both convs ============
// NOTE: harness delivers integer inputs as int32 — edge_index is const int*.
__global__ void hist_kernel(const int* __restrict__ ei, int* __restrict__ counts) {
    int e = blockIdx.x * blockDim.x + threadIdx.x;
    if (e >= Ee) return;
    int d = ei[Ee + e];
    if ((unsigned)d >= (unsigned)Nn) return;   // defensive: drop bad edges
    atomicAdd(&counts[d], 1);
}

// ---- 3-phase multi-block exclusive scan over counts[Nn] ----
__global__ __launch_bounds__(SCAN_B) void scan_sum_kernel(const int* __restrict__ counts,
                                                          int* __restrict__ bsum) {
    int i = blockIdx.x * SCAN_B + threadIdx.x;
    int v = (i < Nn) ? counts[i] : 0;
    for (int o = 32; o > 0; o >>= 1) v += __shfl_down(v, o, 64);
    __shared__ int ws[SCAN_B / 64];
    if ((threadIdx.x & 63) == 0) ws[threadIdx.x >> 6] = v;
    __syncthreads();
    if (threadIdx.x == 0) {
        int s = 0;
        for (int k = 0; k < SCAN_B / 64; ++k) s += ws[k];
        bsum[blockIdx.x] = s;
    }
}

__global__ __launch_bounds__(256) void scan_bsum_kernel(const int* __restrict__ bsum,
                                                        int* __restrict__ boff,
                                                        int* __restrict__ rowptr) {
    __shared__ int lds[256];
    int t = threadIdx.x;
    int v = (t < SCAN_NB) ? bsum[t] : 0;
    lds[t] = v;
    __syncthreads();
    for (int o = 1; o < 256; o <<= 1) {
        int u = (t >= o) ? lds[t - o] : 0;
        __syncthreads();
        lds[t] += u;
        __syncthreads();
    }
    if (t < SCAN_NB) boff[t] = lds[t] - v;
    if (t == 255) rowptr[Nn] = lds[255];
}

__global__ __launch_bounds__(SCAN_B) void scan_blocks_kernel(const int* __restrict__ counts,
                                                             const int* __restrict__ boff,
                                                             int* __restrict__ rowptr,
                                                             int* __restrict__ cursor) {
    __shared__ int lds[SCAN_B];
    int i = blockIdx.x * SCAN_B + threadIdx.x;
    int t = threadIdx.x;
    int v = (i < Nn) ? counts[i] : 0;
    lds[t] = v;
    __syncthreads();
    for (int o = 1; o < SCAN_B; o <<= 1) {
        int u = (t >= o) ? lds[t - o] : 0;
        __syncthreads();
        lds[t] += u;
        __syncthreads();
    }
    if (i < Nn) {
        int excl = lds[t] - v + boff[blockIdx.x];
        rowptr[i] = excl;
        cursor[i] = excl;
    }
}

// fill CSR: per edge store int2{ src | k<<20, bits(ea) }; k found once here.
__global__ void fill_kernel(const int* __restrict__ ei, const float* __restrict__ eattr,
                            const float* __restrict__ st, int* __restrict__ cursor,
                            int2* __restrict__ me) {
    __shared__ float ts[Cc];
    if (threadIdx.x < Cc) ts[threadIdx.x] = st[threadIdx.x];
    __syncthreads();
    int e = blockIdx.x * blockDim.x + threadIdx.x;
    if (e >= Ee) return;
    int s = ei[e];
    int d = ei[Ee + e];
    if ((unsigned)s >= (unsigned)Nn || (unsigned)d >= (unsigned)Nn) return;  // defensive
    float ea = eattr[e];
    int lo = 0, hi = Cc;          // k = count of thresholds < ea
    while (lo < hi) {
        int m = (lo + hi) >> 1;
        if (ts[m] < ea) lo = m + 1; else hi = m;
    }
    int pos = atomicAdd(&cursor[d], 1);
    if ((unsigned)pos >= (unsigned)Ee) return;  // defensive
    me[pos] = make_int2(s | (lo << 20), __float_as_int(ea));
}

// ============ aggregation: out[n] = feat[n] + sum_in relu(feat[src] + e) ============
// one 64-lane wave per node; lanes 0..47 each own a channel PAIR (float2).
__global__ __launch_bounds__(256) void aggregate_kernel(
        const float* __restrict__ feat, const int* __restrict__ rowptr,
        const int2* __restrict__ me, const float4* __restrict__ tab,
        float* __restrict__ out) {
    int node = blockIdx.x * (blockDim.x >> 6) + (threadIdx.x >> 6);
    int lane = threadIdx.x & 63;
    if (node >= Nn || lane >= 48) return;
    const float2* f2 = (const float2*)feat;
    int j = lane;                          // channel pair index, 0..47
    float2 acc = f2[(size_t)node * 48 + j];
    int s = rowptr[node], e = rowptr[node + 1];
    int p = s;
    for (; p + 4 <= e; p += 4) {
        int2 m0 = me[p], m1 = me[p + 1], m2 = me[p + 2], m3 = me[p + 3];
        float2 f0 = f2[(size_t)(m0.x & 0xFFFFF) * 48 + j];
        float2 f1 = f2[(size_t)(m1.x & 0xFFFFF) * 48 + j];
        float2 fq2 = f2[(size_t)(m2.x & 0xFFFFF) * 48 + j];
        float2 f3 = f2[(size_t)(m3.x & 0xFFFFF) * 48 + j];
        float4 t0 = tab[(m0.x >> 20) * 48 + j];
        float4 t1 = tab[(m1.x >> 20) * 48 + j];
        float4 t2 = tab[(m2.x >> 20) * 48 + j];
        float4 t3 = tab[(m3.x >> 20) * 48 + j];
        float ea0 = __int_as_float(m0.y), ea1 = __int_as_float(m1.y);
        float ea2 = __int_as_float(m2.y), ea3 = __int_as_float(m3.y);
        acc.x += fmaxf(f0.x + fmaf(ea0, t0.x, t0.y), 0.f);
        acc.y += fmaxf(f0.y + fmaf(ea0, t0.z, t0.w), 0.f);
        acc.x += fmaxf(f1.x + fmaf(ea1, t1.x, t1.y), 0.f);
        acc.y += fmaxf(f1.y + fmaf(ea1, t1.z, t1.w), 0.f);
        acc.x += fmaxf(fq2.x + fmaf(ea2, t2.x, t2.y), 0.f);
        acc.y += fmaxf(fq2.y + fmaf(ea2, t2.z, t2.w), 0.f);
        acc.x += fmaxf(f3.x + fmaf(ea3, t3.x, t3.y), 0.f);
        acc.y += fmaxf(f3.y + fmaf(ea3, t3.z, t3.w), 0.f);
    }
    for (; p < e; ++p) {
        int2 m0 = me[p];
        float2 f0 = f2[(size_t)(m0.x & 0xFFFFF) * 48 + j];
        float4 t0 = tab[(m0.x >> 20) * 48 + j];
        float ea0 = __int_as_float(m0.y);
        acc.x += fmaxf(f0.x + fmaf(ea0, t0.x, t0.y), 0.f);
        acc.y += fmaxf(f0.y + fmaf(ea0, t0.z, t0.w), 0.f);
    }
    ((float2*)out)[(size_t)node * 48 + j] = acc;
}

// ============ fused 2-layer node MLP via bf16x3 MFMA ============
// out = relu(relu(in@W1+b1)@W2+b2), fp32 emulated as hi/lo bf16 (3 MFMA/product).
// Block: 256 thr = 4 waves, 64 rows; wave w owns rows w*16..w*16+15, all 96 cols.
// LDS: x hi/lo [64][104] bf16 + W^T hi/lo [96][104] bf16 (pad 104: 16B-aligned
// rows, 52-dword stride spreads rows across bank-quads). IN-PLACE SAFE.
#define MLP_PAD 104
__global__ __launch_bounds__(256) void mlp2_kernel(
        const float* __restrict__ in, const float* __restrict__ W1g, const float* __restrict__ b1g,
        const float* __restrict__ W2g, const float* __restrict__ b2g, float* __restrict__ out) {
    __shared__ unsigned short xh[64 * MLP_PAD], xl[64 * MLP_PAD];
    __shared__ unsigned short wth[96 * MLP_PAD], wtl[96 * MLP_PAD];
    __shared__ float bb1[Cc], bb2[Cc];
    int tid = threadIdx.x;
    int row0 = blockIdx.x * 64;

    // stage x tile (hi/lo), 24 elems/thread, coalesced global reads
    for (int t = 0; t < 24; ++t) {
        int idx = tid + t * 256;                 // 0..6143
        int r = idx / Cc, c = idx - r * Cc;
        int gr = row0 + r;
        float v = (gr < Nn) ? in[(size_t)gr * Cc + c] : 0.f;
        unsigned short hi, lo;
        split_bf16(v, hi, lo);
        xh[r * MLP_PAD + c] = hi; xl[r * MLP_PAD + c] = lo;
    }
    // stage W1 transposed (hi/lo): W[k][n] -> wt[n][k]
    for (int t = 0; t < 36; ++t) {
        int idx = tid + t * 256;                 // 0..9215
        int k = idx / Cc, n = idx - k * Cc;
        unsigned short hi, lo;
        split_bf16(W1g[idx], hi, lo);
        wth[n * MLP_PAD + k] = hi; wtl[n * MLP_PAD + k] = lo;
    }
    if (tid < Cc) { bb1[tid] = b1g[tid]; bb2[tid] = b2g[tid]; }
    __syncthreads();

    int lane = tid & 63, w = tid >> 6;
    int li = lane & 15, lg = lane >> 4;          // li: m/n idx; lg: k-group
    int arow = w * 16 + li;                      // A row (A: row=lane&15, k=8*lg+e)

    f32x4 acc[6];
    // ---- layer 1 ----
    for (int nt = 0; nt < 6; ++nt) {
        float bv = bb1[nt * 16 + li];
        acc[nt] = (f32x4){bv, bv, bv, bv};
    }
    for (int k0 = 0; k0 < Cc; k0 += 32) {
        int ko = k0 + lg * 8;
        bf16x8 ah = *(const bf16x8*)&xh[arow * MLP_PAD + ko];
        bf16x8 al = *(const bf16x8*)&xl[arow * MLP_PAD + ko];
        for (int nt = 0; nt < 6; ++nt) {
            bf16x8 bh = *(const bf16x8*)&wth[(nt * 16 + li) * MLP_PAD + ko];
            bf16x8 bl = *(const bf16x8*)&wtl[(nt * 16 + li) * MLP_PAD + ko];
            acc[nt] = __builtin_amdgcn_mfma_f32_16x16x32_bf16(ah, bh, acc[nt], 0, 0, 0);
            acc[nt] = __builtin_amdgcn_mfma_f32_16x16x32_bf16(ah, bl, acc[nt], 0, 0, 0);
            acc[nt] = __builtin_amdgcn_mfma_f32_16x16x32_bf16(al, bh, acc[nt], 0, 0, 0);
        }
    }
    __syncthreads();   // all waves done reading wt & x
    // relu1 -> xh/xl at D layout (row=4*lg+r, col=li; wave-local rows); restage W2
    for (int nt = 0; nt < 6; ++nt) {
        for (int r = 0; r < 4; ++r) {
            float v = fmaxf(acc[nt][r], 0.f);
            int row = w * 16 + lg * 4 + r;
            int col = nt * 16 + li;
            unsigned short hi, lo;
            split_bf16(v, hi, lo);
            xh[row * MLP_PAD + col] = hi; xl[row * MLP_PAD + col] = lo;
        }
    }
    for (int t = 0; t < 36; ++t) {
        int idx = tid + t * 256;
        int k = idx / Cc, n = idx - k * Cc;
        unsigned short hi, lo;
        split_bf16(W2g[idx], hi, lo);
        wth[n * MLP_PAD + k] = hi; wtl[n * MLP_PAD + k] = lo;
    }
    __syncthreads();

    // ---- layer 2 ----
    for (int nt = 0; nt < 6; ++nt) {
        float bv = bb2[nt * 16 + li];
        acc[nt] = (f32x4){bv, bv, bv, bv};
    }
    for (int k0 = 0; k0 < Cc; k0 += 32) {
        int ko = k0 + lg * 8;
        bf16x8 ah = *(const bf16x8*)&xh[arow * MLP_PAD + ko];
        bf16x8 al = *(const bf16x8*)&xl[arow * MLP_PAD + ko];
        for (int nt = 0; nt < 6; ++nt) {
            bf16x8 bh = *(const bf16x8*)&wth[(nt * 16 + li) * MLP_PAD + ko];
            bf16x8 bl = *(const bf16x8*)&wtl[(nt * 16 + li) * MLP_PAD + ko];
            acc[nt] = __builtin_amdgcn_mfma_f32_16x16x32_bf16(ah, bh, acc[nt], 0, 0, 0);
            acc[nt] = __builtin_amdgcn_mfma_f32_16x16x32_bf16(ah, bl, acc[nt], 0, 0, 0);
            acc[nt] = __builtin_amdgcn_mfma_f32_16x16x32_bf16(al, bh, acc[nt], 0, 0, 0);
        }
    }
    // epilogue: relu + store (D layout), guarded for tail rows
    for (int nt = 0; nt < 6; ++nt) {
        for (int r = 0; r < 4; ++r) {
            int grow = row0 + w * 16 + lg * 4 + r;
            if (grow < Nn)
                out[(size_t)grow * Cc + nt * 16 + li] = fmaxf(acc[nt][r], 0.f);
        }
    }
}

extern "C" void kernel_launch(void* const* d_in, const int* in_sizes, int n_in,
                              void* d_out, int out_size, void* d_ws, size_t ws_size,
                              hipStream_t stream) {
    const float* x     = (const float*)d_in[0];
    const int*   ei    = (const int*)d_in[1];     // int64 in ref -> int32 from harness
    const float* eattr = (const float*)d_in[2];
    const float* Wl0   = (const float*)d_in[3];
    const float* bl0   = (const float*)d_in[4];
    const float* Wl1   = (const float*)d_in[5];
    const float* bl1   = (const float*)d_in[6];
    const float* W00   = (const float*)d_in[7];
    const float* b00   = (const float*)d_in[8];
    const float* W01   = (const float*)d_in[9];
    const float* b01   = (const float*)d_in[10];
    const float* W10   = (const float*)d_in[11];
    const float* b10   = (const float*)d_in[12];
    const float* W11   = (const float*)d_in[13];
    const float* b11   = (const float*)d_in[14];
    float* outp = (float*)d_out;

    // workspace carve-up (~26 MB), 256B-aligned
    char* w = (char*)d_ws;
    size_t off = 0;
    auto alloc = [&](size_t bytes) { size_t r = off; off += (bytes + 255) & ~(size_t)255; return r; };
    int*   counts  = (int*)  (w + alloc((size_t)Nn * 4));
    int*   rowptr  = (int*)  (w + alloc((size_t)(Nn + 1) * 4));
    int*   cursor  = (int*)  (w + alloc((size_t)Nn * 4));
    int2*  me      = (int2*) (w + alloc((size_t)Ee * 8));
    float* st      = (float*)(w + alloc((size_t)Cc * 4));
    float* sw      = (float*)(w + alloc((size_t)Cc * 4));
    float* sb      = (float*)(w + alloc((size_t)Cc * 4));
    int*   so      = (int*)  (w + alloc((size_t)Cc * 4));
    int*   bsum    = (int*)  (w + alloc((size_t)SCAN_NB * 4));
    int*   boff    = (int*)  (w + alloc((size_t)SCAN_NB * 4));
    float* tabf    = (float*)(w + alloc((size_t)(Cc + 1) * 2 * Cc * 4));
    float* hpre    = (float*)(w + alloc((size_t)Nn * Cc * 4));
    (void)ws_size; (void)in_sizes; (void)n_in; (void)out_size;

    hipMemsetAsync(counts, 0, (size_t)Nn * 4, stream);
    prep_sort_kernel<<<1, 128, 0, stream>>>(Wl0, bl0, st, sw, sb, so);
    build_table_kernel<<<Cc + 1, 128, 0, stream>>>(sw, sb, so, Wl1, bl1, tabf);
    hist_kernel<<<(Ee + 255) / 256, 256, 0, stream>>>(ei, counts);
    scan_sum_kernel<<<SCAN_NB, SCAN_B, 0, stream>>>(counts, bsum);
    scan_bsum_kernel<<<1, 256, 0, stream>>>(bsum, boff, rowptr);
    scan_blocks_kernel<<<SCAN_NB, SCAN_B, 0, stream>>>(counts, boff, rowptr, cursor);
    fill_kernel<<<(Ee + 255) / 256, 256, 0, stream>>>(ei, eattr, st, cursor, me);

    const float4* tab = (const float4*)tabf;
    // conv 1: agg(x) -> hpre, mlp in-place on hpre
    aggregate_kernel<<<(Nn + 3) / 4, 256, 0, stream>>>(x, rowptr, me, tab, hpre);
    mlp2_kernel<<<(Nn + 63) / 64, 256, 0, stream>>>(hpre, W00, b00, W01, b01, hpre);
    // conv 2: agg(hpre) -> d_out, mlp in-place on d_out
    aggregate_kernel<<<(Nn + 3) / 4, 256, 0, stream>>>(hpre, rowptr, me, tab, outp);
    mlp2_kernel<<<(Nn + 63) / 64, 256, 0, stream>>>(outp, W10, b10, W11, b11, outp);
}

// Round 7
// 288.666 us; speedup vs baseline: 2.2300x; 1.0979x over previous
//
#include <hip/hip_runtime.h>
#include <math.h>

#define Nn 50000
#define Ee 800000
#define Cc 96

#define SCAN_B 256
#define SCAN_NB ((Nn + SCAN_B - 1) / SCAN_B)   // 196

typedef __attribute__((ext_vector_type(8))) __bf16 bf16x8;
typedef __attribute__((ext_vector_type(4))) float f32x4;

// split fp32 into hi/lo bf16 (truncation; lo captures next 8 mantissa bits)
__device__ inline void split_bf16(float v, unsigned short& hi, unsigned short& lo) {
    unsigned u = __float_as_uint(v);
    hi = (unsigned short)(u >> 16);
    float rem = v - __uint_as_float(((unsigned)hi) << 16);
    lo = (unsigned short)(__float_as_uint(rem) >> 16);
}

// ============ prep: sort linear0 hidden units by relu threshold ============
// e(ea) = relu(ea*w0 + b0) @ W_l1 + b_l1 is piecewise-linear in scalar ea.
// Unit c active iff ea > t_c (w0>0) or ea < t_c (w0<0), t_c = -b0/w0.
// With thresholds sorted, k = #{t_i < ea} in [0,96] determines the active set.
__global__ void prep_sort_kernel(const float* __restrict__ Wl0, const float* __restrict__ bl0,
                                 float* __restrict__ st, float* __restrict__ sw,
                                 float* __restrict__ sb, int* __restrict__ so) {
    __shared__ float t_s[Cc];
    int c = threadIdx.x;
    float w = 0.f, b = 0.f, t = 0.f;
    if (c < Cc) {
        w = Wl0[c]; b = bl0[c];
        t = (w != 0.0f) ? (-b / w) : INFINITY;
        t_s[c] = t;
    }
    __syncthreads();
    if (c < Cc) {
        int r = 0;
        for (int j = 0; j < Cc; ++j) {
            float tj = t_s[j];
            r += (tj < t || (tj == t && j < c)) ? 1 : 0;  // stable rank sort
        }
        st[r] = t; sw[r] = w; sb[r] = b; so[r] = c;
    }
}

// Table in gather-friendly layout: tab[k][j] = float4{A[2j], B[2j], A[2j+1], B[2j+1]},
// j = 0..47 channel pairs, k = 0..96 activation patterns. 75 KB.
__global__ void build_table_kernel(const float* __restrict__ sw, const float* __restrict__ sb,
                                   const int* __restrict__ so, const float* __restrict__ Wl1,
                                   const float* __restrict__ bl1,
                                   float* __restrict__ tabf) {
    int k = blockIdx.x;          // 0..96
    int c2 = threadIdx.x;
    if (c2 >= Cc) return;
    float a = 0.f, bacc = bl1[c2];
    for (int i = 0; i < Cc; ++i) {
        float w = sw[i], b = sb[i];
        float wv = Wl1[so[i] * Cc + c2];
        bool act = (w > 0.f) ? (i < k) : ((w < 0.f) ? (i >= k) : (b > 0.f));
        if (act) { a = fmaf(w, wv, a); bacc = fmaf(b, wv, bacc); }
    }
    int base = k * (2 * Cc) + (c2 >> 1) * 4 + ((c2 & 1) << 1);
    tabf[base] = a;
    tabf[base + 1] = bacc;
}

// ============ CSR build (by dst), reused for both convs ============
// NOTE: harness delivers integer inputs as int32 — edge_index is const int*.
__global__ void hist_kernel(const int* __restrict__ ei, int* __restrict__ counts) {
    int e = blockIdx.x * blockDim.x + threadIdx.x;
    if (e >= Ee) return;
    int d = ei[Ee + e];
    if ((unsigned)d >= (unsigned)Nn) return;   // defensive: drop bad edges
    atomicAdd(&counts[d], 1);
}

// ---- 3-phase multi-block exclusive scan over counts[Nn] ----
__global__ __launch_bounds__(SCAN_B) void scan_sum_kernel(const int* __restrict__ counts,
                                                          int* __restrict__ bsum) {
    int i = blockIdx.x * SCAN_B + threadIdx.x;
    int v = (i < Nn) ? counts[i] : 0;
    for (int o = 32; o > 0; o >>= 1) v += __shfl_down(v, o, 64);
    __shared__ int ws[SCAN_B / 64];
    if ((threadIdx.x & 63) == 0) ws[threadIdx.x >> 6] = v;
    __syncthreads();
    if (threadIdx.x == 0) {
        int s = 0;
        for (int k = 0; k < SCAN_B / 64; ++k) s += ws[k];
        bsum[blockIdx.x] = s;
    }
}

__global__ __launch_bounds__(256) void scan_bsum_kernel(const int* __restrict__ bsum,
                                                        int* __restrict__ boff,
                                                        int* __restrict__ rowptr) {
    __shared__ int lds[256];
    int t = threadIdx.x;
    int v = (t < SCAN_NB) ? bsum[t] : 0;
    lds[t] = v;
    __syncthreads();
    for (int o = 1; o < 256; o <<= 1) {
        int u = (t >= o) ? lds[t - o] : 0;
        __syncthreads();
        lds[t] += u;
        __syncthreads();
    }
    if (t < SCAN_NB) boff[t] = lds[t] - v;
    if (t == 255) rowptr[Nn] = lds[255];
}

__global__ __launch_bounds__(SCAN_B) void scan_blocks_kernel(const int* __restrict__ counts,
                                                             const int* __restrict__ boff,
                                                             int* __restrict__ rowptr,
                                                             int* __restrict__ cursor) {
    __shared__ int lds[SCAN_B];
    int i = blockIdx.x * SCAN_B + threadIdx.x;
    int t = threadIdx.x;
    int v = (i < Nn) ? counts[i] : 0;
    lds[t] = v;
    __syncthreads();
    for (int o = 1; o < SCAN_B; o <<= 1) {
        int u = (t >= o) ? lds[t - o] : 0;
        __syncthreads();
        lds[t] += u;
        __syncthreads();
    }
    if (i < Nn) {
        int excl = lds[t] - v + boff[blockIdx.x];
        rowptr[i] = excl;
        cursor[i] = excl;
    }
}

// fill CSR: per edge store int2{ src | k<<20, bits(ea) }; k found once here.
__global__ void fill_kernel(const int* __restrict__ ei, const float* __restrict__ eattr,
                            const float* __restrict__ st, int* __restrict__ cursor,
                            int2* __restrict__ me) {
    __shared__ float ts[Cc];
    if (threadIdx.x < Cc) ts[threadIdx.x] = st[threadIdx.x];
    __syncthreads();
    int e = blockIdx.x * blockDim.x + threadIdx.x;
    if (e >= Ee) return;
    int s = ei[e];
    int d = ei[Ee + e];
    if ((unsigned)s >= (unsigned)Nn || (unsigned)d >= (unsigned)Nn) return;  // defensive
    float ea = eattr[e];
    int lo = 0, hi = Cc;          // k = count of thresholds < ea
    while (lo < hi) {
        int m = (lo + hi) >> 1;
        if (ts[m] < ea) lo = m + 1; else hi = m;
    }
    int pos = atomicAdd(&cursor[d], 1);
    if ((unsigned)pos >= (unsigned)Ee) return;  // defensive
    me[pos] = make_int2(s | (lo << 20), __float_as_int(ea));
}

// ============ aggregation: out[n] = feat[n] + sum_in relu(feat[src] + e) ============
// Persistent blocks: 1024 thr (16 waves), full 75 KB table staged in LDS once,
// then grid-stride wave-per-node. Lanes 0..47 own a channel PAIR (float2).
// Per edge: one wave-uniform 8B meta load + one 8B feat gather (L2/L3) +
// one 16B ds_read (contiguous 768B sweep -> no meaningful bank conflict).
// LDS 74.5 KB -> 2 blocks/CU -> 32 waves/CU.
#define AGG_NB 512
__global__ __launch_bounds__(1024) void aggregate_kernel(
        const float* __restrict__ feat, const int* __restrict__ rowptr,
        const int2* __restrict__ me, const float4* __restrict__ tab,
        float* __restrict__ out) {
    __shared__ float4 tl[(Cc + 1) * 48];   // 97*48*16 = 74496 B
    int tid = threadIdx.x;
    for (int i = tid; i < (Cc + 1) * 48; i += 1024) tl[i] = tab[i];
    __syncthreads();
    int wave = tid >> 6, lane = tid & 63;
    if (lane >= 48) return;               // no further syncs below
    int j = lane;                          // channel pair index, 0..47
    const float2* f2 = (const float2*)feat;
    for (int node = blockIdx.x * 16 + wave; node < Nn; node += AGG_NB * 16) {
        float2 acc = f2[(size_t)node * 48 + j];
        int s = rowptr[node], e = rowptr[node + 1];
        int p = s;
        for (; p + 4 <= e; p += 4) {
            int2 m0 = me[p], m1 = me[p + 1], m2 = me[p + 2], m3 = me[p + 3];
            float2 f0 = f2[(size_t)(m0.x & 0xFFFFF) * 48 + j];
            float2 f1 = f2[(size_t)(m1.x & 0xFFFFF) * 48 + j];
            float2 fq2 = f2[(size_t)(m2.x & 0xFFFFF) * 48 + j];
            float2 f3 = f2[(size_t)(m3.x & 0xFFFFF) * 48 + j];
            float4 t0 = tl[(m0.x >> 20) * 48 + j];
            float4 t1 = tl[(m1.x >> 20) * 48 + j];
            float4 t2 = tl[(m2.x >> 20) * 48 + j];
            float4 t3 = tl[(m3.x >> 20) * 48 + j];
            float ea0 = __int_as_float(m0.y), ea1 = __int_as_float(m1.y);
            float ea2 = __int_as_float(m2.y), ea3 = __int_as_float(m3.y);
            acc.x += fmaxf(f0.x + fmaf(ea0, t0.x, t0.y), 0.f);
            acc.y += fmaxf(f0.y + fmaf(ea0, t0.z, t0.w), 0.f);
            acc.x += fmaxf(f1.x + fmaf(ea1, t1.x, t1.y), 0.f);
            acc.y += fmaxf(f1.y + fmaf(ea1, t1.z, t1.w), 0.f);
            acc.x += fmaxf(fq2.x + fmaf(ea2, t2.x, t2.y), 0.f);
            acc.y += fmaxf(fq2.y + fmaf(ea2, t2.z, t2.w), 0.f);
            acc.x += fmaxf(f3.x + fmaf(ea3, t3.x, t3.y), 0.f);
            acc.y += fmaxf(f3.y + fmaf(ea3, t3.z, t3.w), 0.f);
        }
        for (; p < e; ++p) {
            int2 m0 = me[p];
            float2 f0 = f2[(size_t)(m0.x & 0xFFFFF) * 48 + j];
            float4 t0 = tl[(m0.x >> 20) * 48 + j];
            float ea0 = __int_as_float(m0.y);
            acc.x += fmaxf(f0.x + fmaf(ea0, t0.x, t0.y), 0.f);
            acc.y += fmaxf(f0.y + fmaf(ea0, t0.z, t0.w), 0.f);
        }
        ((float2*)out)[(size_t)node * 48 + j] = acc;
    }
}

// ============ fused 2-layer node MLP via bf16x3 MFMA ============
// out = relu(relu(in@W1+b1)@W2+b2), fp32 emulated as hi/lo bf16 (3 MFMA/product).
// Block: 256 thr = 4 waves, 64 rows; wave w owns rows w*16..w*16+15, all 96 cols.
// LDS: x hi/lo [64][104] bf16 + W^T hi/lo [96][104] bf16. IN-PLACE SAFE.
#define MLP_PAD 104
__global__ __launch_bounds__(256) void mlp2_kernel(
        const float* __restrict__ in, const float* __restrict__ W1g, const float* __restrict__ b1g,
        const float* __restrict__ W2g, const float* __restrict__ b2g, float* __restrict__ out) {
    __shared__ unsigned short xh[64 * MLP_PAD], xl[64 * MLP_PAD];
    __shared__ unsigned short wth[96 * MLP_PAD], wtl[96 * MLP_PAD];
    __shared__ float bb1[Cc], bb2[Cc];
    int tid = threadIdx.x;
    int row0 = blockIdx.x * 64;

    for (int t = 0; t < 24; ++t) {
        int idx = tid + t * 256;                 // 0..6143
        int r = idx / Cc, c = idx - r * Cc;
        int gr = row0 + r;
        float v = (gr < Nn) ? in[(size_t)gr * Cc + c] : 0.f;
        unsigned short hi, lo;
        split_bf16(v, hi, lo);
        xh[r * MLP_PAD + c] = hi; xl[r * MLP_PAD + c] = lo;
    }
    for (int t = 0; t < 36; ++t) {
        int idx = tid + t * 256;                 // 0..9215
        int k = idx / Cc, n = idx - k * Cc;
        unsigned short hi, lo;
        split_bf16(W1g[idx], hi, lo);
        wth[n * MLP_PAD + k] = hi; wtl[n * MLP_PAD + k] = lo;
    }
    if (tid < Cc) { bb1[tid] = b1g[tid]; bb2[tid] = b2g[tid]; }
    __syncthreads();

    int lane = tid & 63, w = tid >> 6;
    int li = lane & 15, lg = lane >> 4;          // li: m/n idx; lg: k-group
    int arow = w * 16 + li;                      // A row (A: row=lane&15, k=8*lg+e)

    f32x4 acc[6];
    // ---- layer 1 ----
    for (int nt = 0; nt < 6; ++nt) {
        float bv = bb1[nt * 16 + li];
        acc[nt] = (f32x4){bv, bv, bv, bv};
    }
    for (int k0 = 0; k0 < Cc; k0 += 32) {
        int ko = k0 + lg * 8;
        bf16x8 ah = *(const bf16x8*)&xh[arow * MLP_PAD + ko];
        bf16x8 al = *(const bf16x8*)&xl[arow * MLP_PAD + ko];
        for (int nt = 0; nt < 6; ++nt) {
            bf16x8 bh = *(const bf16x8*)&wth[(nt * 16 + li) * MLP_PAD + ko];
            bf16x8 bl = *(const bf16x8*)&wtl[(nt * 16 + li) * MLP_PAD + ko];
            acc[nt] = __builtin_amdgcn_mfma_f32_16x16x32_bf16(ah, bh, acc[nt], 0, 0, 0);
            acc[nt] = __builtin_amdgcn_mfma_f32_16x16x32_bf16(ah, bl, acc[nt], 0, 0, 0);
            acc[nt] = __builtin_amdgcn_mfma_f32_16x16x32_bf16(al, bh, acc[nt], 0, 0, 0);
        }
    }
    __syncthreads();   // all waves done reading wt & x
    for (int nt = 0; nt < 6; ++nt) {
        for (int r = 0; r < 4; ++r) {
            float v = fmaxf(acc[nt][r], 0.f);
            int row = w * 16 + lg * 4 + r;
            int col = nt * 16 + li;
            unsigned short hi, lo;
            split_bf16(v, hi, lo);
            xh[row * MLP_PAD + col] = hi; xl[row * MLP_PAD + col] = lo;
        }
    }
    for (int t = 0; t < 36; ++t) {
        int idx = tid + t * 256;
        int k = idx / Cc, n = idx - k * Cc;
        unsigned short hi, lo;
        split_bf16(W2g[idx], hi, lo);
        wth[n * MLP_PAD + k] = hi; wtl[n * MLP_PAD + k] = lo;
    }
    __syncthreads();

    // ---- layer 2 ----
    for (int nt = 0; nt < 6; ++nt) {
        float bv = bb2[nt * 16 + li];
        acc[nt] = (f32x4){bv, bv, bv, bv};
    }
    for (int k0 = 0; k0 < Cc; k0 += 32) {
        int ko = k0 + lg * 8;
        bf16x8 ah = *(const bf16x8*)&xh[arow * MLP_PAD + ko];
        bf16x8 al = *(const bf16x8*)&xl[arow * MLP_PAD + ko];
        for (int nt = 0; nt < 6; ++nt) {
            bf16x8 bh = *(const bf16x8*)&wth[(nt * 16 + li) * MLP_PAD + ko];
            bf16x8 bl = *(const bf16x8*)&wtl[(nt * 16 + li) * MLP_PAD + ko];
            acc[nt] = __builtin_amdgcn_mfma_f32_16x16x32_bf16(ah, bh, acc[nt], 0, 0, 0);
            acc[nt] = __builtin_amdgcn_mfma_f32_16x16x32_bf16(ah, bl, acc[nt], 0, 0, 0);
            acc[nt] = __builtin_amdgcn_mfma_f32_16x16x32_bf16(al, bh, acc[nt], 0, 0, 0);
        }
    }
    for (int nt = 0; nt < 6; ++nt) {
        for (int r = 0; r < 4; ++r) {
            int grow = row0 + w * 16 + lg * 4 + r;
            if (grow < Nn)
                out[(size_t)grow * Cc + nt * 16 + li] = fmaxf(acc[nt][r], 0.f);
        }
    }
}

extern "C" void kernel_launch(void* const* d_in, const int* in_sizes, int n_in,
                              void* d_out, int out_size, void* d_ws, size_t ws_size,
                              hipStream_t stream) {
    const float* x     = (const float*)d_in[0];
    const int*   ei    = (const int*)d_in[1];     // int64 in ref -> int32 from harness
    const float* eattr = (const float*)d_in[2];
    const float* Wl0   = (const float*)d_in[3];
    const float* bl0   = (const float*)d_in[4];
    const float* Wl1   = (const float*)d_in[5];
    const float* bl1   = (const float*)d_in[6];
    const float* W00   = (const float*)d_in[7];
    const float* b00   = (const float*)d_in[8];
    const float* W01   = (const float*)d_in[9];
    const float* b01   = (const float*)d_in[10];
    const float* W10   = (const float*)d_in[11];
    const float* b10   = (const float*)d_in[12];
    const float* W11   = (const float*)d_in[13];
    const float* b11   = (const float*)d_in[14];
    float* outp = (float*)d_out;

    // workspace carve-up (~26 MB), 256B-aligned
    char* w = (char*)d_ws;
    size_t off = 0;
    auto alloc = [&](size_t bytes) { size_t r = off; off += (bytes + 255) & ~(size_t)255; return r; };
    int*   counts  = (int*)  (w + alloc((size_t)Nn * 4));
    int*   rowptr  = (int*)  (w + alloc((size_t)(Nn + 1) * 4));
    int*   cursor  = (int*)  (w + alloc((size_t)Nn * 4));
    int2*  me      = (int2*) (w + alloc((size_t)Ee * 8));
    float* st      = (float*)(w + alloc((size_t)Cc * 4));
    float* sw      = (float*)(w + alloc((size_t)Cc * 4));
    float* sb      = (float*)(w + alloc((size_t)Cc * 4));
    int*   so      = (int*)  (w + alloc((size_t)Cc * 4));
    int*   bsum    = (int*)  (w + alloc((size_t)SCAN_NB * 4));
    int*   boff    = (int*)  (w + alloc((size_t)SCAN_NB * 4));
    float* tabf    = (float*)(w + alloc((size_t)(Cc + 1) * 2 * Cc * 4));
    float* hpre    = (float*)(w + alloc((size_t)Nn * Cc * 4));
    (void)ws_size; (void)in_sizes; (void)n_in; (void)out_size;

    hipMemsetAsync(counts, 0, (size_t)Nn * 4, stream);
    prep_sort_kernel<<<1, 128, 0, stream>>>(Wl0, bl0, st, sw, sb, so);
    build_table_kernel<<<Cc + 1, 128, 0, stream>>>(sw, sb, so, Wl1, bl1, tabf);
    hist_kernel<<<(Ee + 255) / 256, 256, 0, stream>>>(ei, counts);
    scan_sum_kernel<<<SCAN_NB, SCAN_B, 0, stream>>>(counts, bsum);
    scan_bsum_kernel<<<1, 256, 0, stream>>>(bsum, boff, rowptr);
    scan_blocks_kernel<<<SCAN_NB, SCAN_B, 0, stream>>>(counts, boff, rowptr, cursor);
    fill_kernel<<<(Ee + 255) / 256, 256, 0, stream>>>(ei, eattr, st, cursor, me);

    const float4* tab = (const float4*)tabf;
    // conv 1: agg(x) -> hpre, mlp in-place on hpre
    aggregate_kernel<<<AGG_NB, 1024, 0, stream>>>(x, rowptr, me, tab, hpre);
    mlp2_kernel<<<(Nn + 63) / 64, 256, 0, stream>>>(hpre, W00, b00, W01, b01, hpre);
    // conv 2: agg(hpre) -> d_out, mlp in-place on d_out
    aggregate_kernel<<<AGG_NB, 1024, 0, stream>>>(hpre, rowptr, me, tab, outp);
    mlp2_kernel<<<(Nn + 63) / 64, 256, 0, stream>>>(outp, W10, b10, W11, b11, outp);
}